// Round 10
// baseline (244.799 us; speedup 1.0000x reference)
//
#include <hip/hip_runtime.h>
#include <math.h>

#define NSEG 1024
#define MINPIX 8.0f
#define EPSF 1e-6f

#define QSCALE 8192.0f
#define FMASK ((1ull << 26) - 1)
#define CSHIFT 26
#define NSHIFT 52

typedef unsigned long long u64;
typedef unsigned int u32;

// ---------- ABLATION PROBE A: stage1's exact 3-stream load pattern, NO atomics.
// Measures the pure-streaming ceiling for this access pattern.
__global__ __launch_bounds__(256) void fl_probeA(
    const float* __restrict__ pred, const float* __restrict__ clean,
    const int* __restrict__ inst, u64* __restrict__ sink,
    int bpb, int npix)
{
    const int b  = blockIdx.x / bpb;
    const int kb = blockIdx.x - b * bpb;
    int chunk = (npix + bpb - 1) / bpb;
    chunk = (chunk + 1023) & ~1023;
    const int start = kb * chunk;
    const int end   = min(start + chunk, npix);
    const size_t base = (size_t)b * (size_t)npix;

    float sp = 0.f, sc = 0.f; u32 sm = 0;
    for (int i = start + (int)threadIdx.x * 4; i < end; i += 256 * 4) {
        const float4 p4 = *reinterpret_cast<const float4*>(pred  + base + i);
        const float4 c4 = *reinterpret_cast<const float4*>(clean + base + i);
        const int4   m4 = *reinterpret_cast<const int4*>(inst   + base + i);
        sp += p4.x + p4.y + p4.z + p4.w;
        sc += c4.x + c4.y + c4.z + c4.w;
        sm ^= (u32)(m4.x + m4.y + m4.z + m4.w);
    }
    sink[(size_t)blockIdx.x * 256 + threadIdx.x] =
        ((u64)__float_as_uint(sp) << 32) ^ (u64)__float_as_uint(sc) ^ (u64)sm;
}

// ---------- ABLATION PROBE B: stage1's exact LDS u64 atomic burst (same count,
// pseudo-random ids matching the uniform-random data), NO global loads.
// Measures the DS atomic pipe in isolation.
__global__ __launch_bounds__(256) void fl_probeB(
    u64* __restrict__ sink, int iters)
{
    __shared__ u64 s_h[NSEG];
    for (int i = threadIdx.x; i < NSEG; i += 256) s_h[i] = 0ull;
    __syncthreads();
    u32 x = (blockIdx.x * 256u + threadIdx.x) * 2654435761u + 12345u;
    for (int k = 0; k < iters; ++k) {
        const u32 id = (x >> 13) & (NSEG - 1);
        x = x * 1664525u + 1013904223u;
        atomicAdd(&s_h[id], (u64)(threadIdx.x + k) | (1ull << NSHIFT));
    }
    __syncthreads();
    u64* out = sink + (size_t)blockIdx.x * NSEG;
    for (int i = threadIdx.x; i < NSEG; i += 256) out[i] = s_h[i];
}

// ---------- Stage 1: unchanged R7 version (1 packed u64 atomic / pixel).
__global__ __launch_bounds__(256) void fl_stage1(
    const float* __restrict__ pred, const float* __restrict__ clean,
    const int* __restrict__ inst, u64* __restrict__ partials,
    int bpb, int npix)
{
    __shared__ u64 s_h[NSEG];
    const int b  = blockIdx.x / bpb;
    const int kb = blockIdx.x - b * bpb;
    for (int i = threadIdx.x; i < NSEG; i += 256) s_h[i] = 0ull;
    __syncthreads();

    int chunk = (npix + bpb - 1) / bpb;
    chunk = (chunk + 1023) & ~1023;
    const int start = kb * chunk;
    const int end   = min(start + chunk, npix);
    const size_t base = (size_t)b * (size_t)npix;

    for (int i = start + (int)threadIdx.x * 4; i < end; i += 256 * 4) {
        const float4 p4 = *reinterpret_cast<const float4*>(pred  + base + i);
        const float4 c4 = *reinterpret_cast<const float4*>(clean + base + i);
        const int4   m4 = *reinterpret_cast<const int4*>(inst   + base + i);
        {
            const u32 pf = (u32)(p4.x * QSCALE + 0.5f);
            const u32 cf = (u32)(c4.x * QSCALE + 0.5f);
            atomicAdd(&s_h[m4.x], (u64)pf | ((u64)cf << CSHIFT) | (1ull << NSHIFT));
        }
        {
            const u32 pf = (u32)(p4.y * QSCALE + 0.5f);
            const u32 cf = (u32)(c4.y * QSCALE + 0.5f);
            atomicAdd(&s_h[m4.y], (u64)pf | ((u64)cf << CSHIFT) | (1ull << NSHIFT));
        }
        {
            const u32 pf = (u32)(p4.z * QSCALE + 0.5f);
            const u32 cf = (u32)(c4.z * QSCALE + 0.5f);
            atomicAdd(&s_h[m4.z], (u64)pf | ((u64)cf << CSHIFT) | (1ull << NSHIFT));
        }
        {
            const u32 pf = (u32)(p4.w * QSCALE + 0.5f);
            const u32 cf = (u32)(c4.w * QSCALE + 0.5f);
            atomicAdd(&s_h[m4.w], (u64)pf | ((u64)cf << CSHIFT) | (1ull << NSHIFT));
        }
    }
    __syncthreads();

    u64* out = partials + (size_t)blockIdx.x * NSEG;
    for (int i = threadIdx.x; i < NSEG; i += 256) out[i] = s_h[i];
}

// Stage 2: unchanged.
__global__ __launch_bounds__(128) void fl_stage2(
    const u64* __restrict__ partials, float* __restrict__ bres, int bpb)
{
    const int b = blockIdx.x >> 3;
    const int q = blockIdx.x & 7;
    const int s = q * 128 + threadIdx.x;
    const u64* base = partials + (size_t)b * bpb * NSEG + s;

    u32 sp = 0, sc = 0, sn = 0;
    #pragma unroll 8
    for (int k = 0; k < bpb; ++k) {
        const u64 v = base[(size_t)k * NSEG];
        sp += (u32)(v & FMASK);
        sc += (u32)((v >> CSHIFT) & FMASK);
        sn += (u32)(v >> NSHIFT);
    }
    const float cn  = (float)sn;
    const float den = fmaxf(cn, 1.0f);
    const float pm  = ((float)sp * (1.0f / QSCALE)) / den;
    const float tm  = ((float)sc * (1.0f / QSCALE)) / den;
    const bool  valid = (cn >= MINPIX) && (s > 0);
    const float v  = valid ? 1.0f : 0.0f;
    const float pc = fminf(fmaxf(pm, EPSF), 1.0f - EPSF);
    const float bce = -(tm * logf(pc) + (1.0f - tm) * log1pf(-pc));
    const float tmask = (valid && tm > 0.5f) ? 1.0f : 0.0f;
    const float nmask = (valid && tm <= 0.5f) ? 1.0f : 0.0f;

    float vals[6];
    vals[0] = bce * v;
    vals[1] = v;
    vals[2] = pm * tmask;
    vals[3] = tmask;
    vals[4] = pm * nmask;
    vals[5] = nmask;

    #pragma unroll
    for (int off = 32; off > 0; off >>= 1)
        #pragma unroll
        for (int j = 0; j < 6; ++j) vals[j] += __shfl_down(vals[j], off);

    __shared__ float red[2][6];
    const int wid  = threadIdx.x >> 6;
    const int lane = threadIdx.x & 63;
    if (lane == 0)
        for (int j = 0; j < 6; ++j) red[wid][j] = vals[j];
    __syncthreads();
    if (threadIdx.x == 0)
        for (int j = 0; j < 6; ++j) bres[blockIdx.x * 6 + j] = red[0][j] + red[1][j];
}

// Stage 3: unchanged.
__global__ __launch_bounds__(128) void fl_stage3(
    const float* __restrict__ bres, float* __restrict__ out)
{
    const int i = threadIdx.x;
    float v[6];
    #pragma unroll
    for (int j = 0; j < 6; ++j) v[j] = bres[i * 6 + j];

    #pragma unroll
    for (int off = 4; off > 0; off >>= 1)
        #pragma unroll
        for (int j = 0; j < 6; ++j) v[j] += __shfl_down(v[j], off, 8);

    float acc[6] = {0.f, 0.f, 0.f, 0.f, 0.f, 0.f};
    if ((i & 7) == 0) {
        const float loss_b = v[0] / fmaxf(v[1], 1.0f);
        const float bv = (v[1] > 0.f) ? 1.f : 0.f;
        const float ct = v[2] / fmaxf(v[3], 1.0f);
        const float ht = (v[3] > 0.f) ? 1.f : 0.f;
        const float cm = v[4] / fmaxf(v[5], 1.0f);
        const float hn = (v[5] > 0.f) ? 1.f : 0.f;
        acc[0] = loss_b * bv; acc[1] = bv;
        acc[2] = ct * ht;     acc[3] = ht;
        acc[4] = cm * hn;     acc[5] = hn;
    }

    #pragma unroll
    for (int off = 32; off > 0; off >>= 1)
        #pragma unroll
        for (int j = 0; j < 6; ++j) acc[j] += __shfl_down(acc[j], off);

    __shared__ float red[2][6];
    const int wid  = threadIdx.x >> 6;
    const int lane = threadIdx.x & 63;
    if (lane == 0)
        for (int j = 0; j < 6; ++j) red[wid][j] = acc[j];
    __syncthreads();
    if (threadIdx.x == 0) {
        float r[6];
        for (int j = 0; j < 6; ++j) r[j] = red[0][j] + red[1][j];
        const float vc = r[1];
        out[0] = (vc > 0.f) ? r[0] / fmaxf(vc, 1.f) : 0.0f;
        out[1] = 0.0f;
        out[2] = (vc > 0.f && r[3] > 0.f) ? r[2] / fmaxf(r[3], 1.f) : -1.0f;
        out[3] = (vc > 0.f && r[5] > 0.f) ? r[4] / fmaxf(r[5], 1.f) : -1.0f;
    }
}

extern "C" void kernel_launch(void* const* d_in, const int* in_sizes, int n_in,
                              void* d_out, int out_size, void* d_ws, size_t ws_size,
                              hipStream_t stream)
{
    const float* pred  = (const float*)d_in[0];
    const float* clean = (const float*)d_in[1];
    const int*   inst  = (const int*)d_in[2];
    float* out = (float*)d_out;

    const int B = 16;
    const int total = in_sizes[0];          // 16777216
    const int npix  = total / B;

    const size_t per_blk_bytes = (size_t)NSEG * sizeof(u64);        // 8 KB
    int bpb = 128;                                                   // 2048 blocks
    size_t need;
    for (;;) {
        const size_t partials_b = (size_t)B * bpb * per_blk_bytes;   // 16 MB
        const size_t sinkA_b    = (size_t)B * bpb * 256 * sizeof(u64); // 4 MB
        const size_t bres_b     = (size_t)B * 8 * 6 * sizeof(float);
        need = partials_b + sinkA_b + bres_b;
        if (need <= ws_size || bpb == 1) break;
        bpb >>= 1;
    }

    u64*   partials = (u64*)d_ws;                                    // probes B sink too (overwritten by stage1)
    u64*   sinkA    = (u64*)((char*)d_ws + (size_t)B * bpb * per_blk_bytes);
    float* bres     = (float*)((char*)sinkA + (size_t)B * bpb * 256 * sizeof(u64));

    // Ablation probes (scratch-only; stage1 later fully overwrites partials).
    fl_probeA<<<dim3(B * bpb), dim3(256), 0, stream>>>(pred, clean, inst, sinkA, bpb, npix);
    fl_probeB<<<dim3(B * bpb), dim3(256), 0, stream>>>(partials, 32);

    // Real pipeline (R7 form, unchanged).
    fl_stage1<<<dim3(B * bpb), dim3(256), 0, stream>>>(pred, clean, inst, partials, bpb, npix);
    fl_stage2<<<dim3(B * 8), dim3(128), 0, stream>>>(partials, bres, bpb);
    fl_stage3<<<dim3(1), dim3(128), 0, stream>>>(bres, out);
}

// Round 11
// 235.928 us; speedup vs baseline: 1.0376x; 1.0376x over previous
//
#include <hip/hip_runtime.h>
#include <math.h>

#define NSEG 1024
#define MINPIX 8.0f
#define EPSF 1e-6f

#define QSCALE 8192.0f
#define FMASK ((1ull << 26) - 1)
#define CSHIFT 26
#define NSHIFT 52

typedef unsigned long long u64;
typedef unsigned int u32;

// ---------- PROBE C: load-only, GRID-STRIDE-WITHIN-BATCH mapping.
// R10's probeA (block-chunk mapping) = 72us @ 2.8 TB/s effective. If the wall
// is DRAM row-buffer thrash from 6144 scattered 4KB stripes, this dense
// moving-window mapping should hit ~5 TB/s -> ~40us.
__global__ __launch_bounds__(256) void fl_probeC(
    const float* __restrict__ pred, const float* __restrict__ clean,
    const int* __restrict__ inst, u64* __restrict__ sink,
    int bpb, int npix)
{
    const int b  = blockIdx.x / bpb;
    const int kb = blockIdx.x - b * bpb;
    const size_t base = (size_t)b * (size_t)npix;
    const int stride = bpb * 256 * 4;

    float sp = 0.f, sc = 0.f; u32 sm = 0;
    for (int i = (kb * 256 + (int)threadIdx.x) * 4; i < npix; i += stride) {
        const float4 p4 = *reinterpret_cast<const float4*>(pred  + base + i);
        const float4 c4 = *reinterpret_cast<const float4*>(clean + base + i);
        const int4   m4 = *reinterpret_cast<const int4*>(inst   + base + i);
        sp += p4.x + p4.y + p4.z + p4.w;
        sc += c4.x + c4.y + c4.z + c4.w;
        sm ^= (u32)(m4.x + m4.y + m4.z + m4.w);
    }
    sink[(size_t)blockIdx.x * 256 + threadIdx.x] =
        ((u64)__float_as_uint(sp) << 32) ^ (u64)__float_as_uint(sc) ^ (u64)sm;
}

// ---------- Stage 1: R7 body, ONLY the index mapping changed to
// grid-stride-within-batch (single lever this round).
__global__ __launch_bounds__(256) void fl_stage1(
    const float* __restrict__ pred, const float* __restrict__ clean,
    const int* __restrict__ inst, u64* __restrict__ partials,
    int bpb, int npix)
{
    __shared__ u64 s_h[NSEG];
    const int b  = blockIdx.x / bpb;
    const int kb = blockIdx.x - b * bpb;
    for (int i = threadIdx.x; i < NSEG; i += 256) s_h[i] = 0ull;
    __syncthreads();

    const size_t base = (size_t)b * (size_t)npix;
    const int stride = bpb * 256 * 4;

    for (int i = (kb * 256 + (int)threadIdx.x) * 4; i < npix; i += stride) {
        const float4 p4 = *reinterpret_cast<const float4*>(pred  + base + i);
        const float4 c4 = *reinterpret_cast<const float4*>(clean + base + i);
        const int4   m4 = *reinterpret_cast<const int4*>(inst   + base + i);
        {
            const u32 pf = (u32)(p4.x * QSCALE + 0.5f);
            const u32 cf = (u32)(c4.x * QSCALE + 0.5f);
            atomicAdd(&s_h[m4.x], (u64)pf | ((u64)cf << CSHIFT) | (1ull << NSHIFT));
        }
        {
            const u32 pf = (u32)(p4.y * QSCALE + 0.5f);
            const u32 cf = (u32)(c4.y * QSCALE + 0.5f);
            atomicAdd(&s_h[m4.y], (u64)pf | ((u64)cf << CSHIFT) | (1ull << NSHIFT));
        }
        {
            const u32 pf = (u32)(p4.z * QSCALE + 0.5f);
            const u32 cf = (u32)(c4.z * QSCALE + 0.5f);
            atomicAdd(&s_h[m4.z], (u64)pf | ((u64)cf << CSHIFT) | (1ull << NSHIFT));
        }
        {
            const u32 pf = (u32)(p4.w * QSCALE + 0.5f);
            const u32 cf = (u32)(c4.w * QSCALE + 0.5f);
            atomicAdd(&s_h[m4.w], (u64)pf | ((u64)cf << CSHIFT) | (1ull << NSHIFT));
        }
    }
    __syncthreads();

    u64* out = partials + (size_t)blockIdx.x * NSEG;
    for (int i = threadIdx.x; i < NSEG; i += 256) out[i] = s_h[i];
}

// Stage 2: unchanged (partition-agnostic: sums all per-block partials).
__global__ __launch_bounds__(128) void fl_stage2(
    const u64* __restrict__ partials, float* __restrict__ bres, int bpb)
{
    const int b = blockIdx.x >> 3;
    const int q = blockIdx.x & 7;
    const int s = q * 128 + threadIdx.x;
    const u64* base = partials + (size_t)b * bpb * NSEG + s;

    u32 sp = 0, sc = 0, sn = 0;
    #pragma unroll 8
    for (int k = 0; k < bpb; ++k) {
        const u64 v = base[(size_t)k * NSEG];
        sp += (u32)(v & FMASK);
        sc += (u32)((v >> CSHIFT) & FMASK);
        sn += (u32)(v >> NSHIFT);
    }
    const float cn  = (float)sn;
    const float den = fmaxf(cn, 1.0f);
    const float pm  = ((float)sp * (1.0f / QSCALE)) / den;
    const float tm  = ((float)sc * (1.0f / QSCALE)) / den;
    const bool  valid = (cn >= MINPIX) && (s > 0);
    const float v  = valid ? 1.0f : 0.0f;
    const float pc = fminf(fmaxf(pm, EPSF), 1.0f - EPSF);
    const float bce = -(tm * logf(pc) + (1.0f - tm) * log1pf(-pc));
    const float tmask = (valid && tm > 0.5f) ? 1.0f : 0.0f;
    const float nmask = (valid && tm <= 0.5f) ? 1.0f : 0.0f;

    float vals[6];
    vals[0] = bce * v;
    vals[1] = v;
    vals[2] = pm * tmask;
    vals[3] = tmask;
    vals[4] = pm * nmask;
    vals[5] = nmask;

    #pragma unroll
    for (int off = 32; off > 0; off >>= 1)
        #pragma unroll
        for (int j = 0; j < 6; ++j) vals[j] += __shfl_down(vals[j], off);

    __shared__ float red[2][6];
    const int wid  = threadIdx.x >> 6;
    const int lane = threadIdx.x & 63;
    if (lane == 0)
        for (int j = 0; j < 6; ++j) red[wid][j] = vals[j];
    __syncthreads();
    if (threadIdx.x == 0)
        for (int j = 0; j < 6; ++j) bres[blockIdx.x * 6 + j] = red[0][j] + red[1][j];
}

// Stage 3: unchanged.
__global__ __launch_bounds__(128) void fl_stage3(
    const float* __restrict__ bres, float* __restrict__ out)
{
    const int i = threadIdx.x;
    float v[6];
    #pragma unroll
    for (int j = 0; j < 6; ++j) v[j] = bres[i * 6 + j];

    #pragma unroll
    for (int off = 4; off > 0; off >>= 1)
        #pragma unroll
        for (int j = 0; j < 6; ++j) v[j] += __shfl_down(v[j], off, 8);

    float acc[6] = {0.f, 0.f, 0.f, 0.f, 0.f, 0.f};
    if ((i & 7) == 0) {
        const float loss_b = v[0] / fmaxf(v[1], 1.0f);
        const float bv = (v[1] > 0.f) ? 1.f : 0.f;
        const float ct = v[2] / fmaxf(v[3], 1.0f);
        const float ht = (v[3] > 0.f) ? 1.f : 0.f;
        const float cm = v[4] / fmaxf(v[5], 1.0f);
        const float hn = (v[5] > 0.f) ? 1.f : 0.f;
        acc[0] = loss_b * bv; acc[1] = bv;
        acc[2] = ct * ht;     acc[3] = ht;
        acc[4] = cm * hn;     acc[5] = hn;
    }

    #pragma unroll
    for (int off = 32; off > 0; off >>= 1)
        #pragma unroll
        for (int j = 0; j < 6; ++j) acc[j] += __shfl_down(acc[j], off);

    __shared__ float red[2][6];
    const int wid  = threadIdx.x >> 6;
    const int lane = threadIdx.x & 63;
    if (lane == 0)
        for (int j = 0; j < 6; ++j) red[wid][j] = acc[j];
    __syncthreads();
    if (threadIdx.x == 0) {
        float r[6];
        for (int j = 0; j < 6; ++j) r[j] = red[0][j] + red[1][j];
        const float vc = r[1];
        out[0] = (vc > 0.f) ? r[0] / fmaxf(vc, 1.f) : 0.0f;
        out[1] = 0.0f;
        out[2] = (vc > 0.f && r[3] > 0.f) ? r[2] / fmaxf(r[3], 1.f) : -1.0f;
        out[3] = (vc > 0.f && r[5] > 0.f) ? r[4] / fmaxf(r[5], 1.f) : -1.0f;
    }
}

extern "C" void kernel_launch(void* const* d_in, const int* in_sizes, int n_in,
                              void* d_out, int out_size, void* d_ws, size_t ws_size,
                              hipStream_t stream)
{
    const float* pred  = (const float*)d_in[0];
    const float* clean = (const float*)d_in[1];
    const int*   inst  = (const int*)d_in[2];
    float* out = (float*)d_out;

    const int B = 16;
    const int total = in_sizes[0];          // 16777216
    const int npix  = total / B;

    const size_t per_blk_bytes = (size_t)NSEG * sizeof(u64);        // 8 KB
    int bpb = 128;                                                   // 2048 blocks
    for (;;) {
        const size_t partials_b = (size_t)B * bpb * per_blk_bytes;   // 16 MB
        const size_t bres_b     = (size_t)B * 8 * 6 * sizeof(float);
        if (partials_b + bres_b <= ws_size || bpb == 1) break;
        bpb >>= 1;
    }

    u64*   partials = (u64*)d_ws;   // probeC sinks into the first 4 MB; stage1 fully overwrites
    float* bres     = (float*)((char*)d_ws + (size_t)B * bpb * per_blk_bytes);

    // Load-only probe with the NEW mapping (A/B against R10's probeA=72us).
    fl_probeC<<<dim3(B * bpb), dim3(256), 0, stream>>>(pred, clean, inst, partials, bpb, npix);

    // Real pipeline.
    fl_stage1<<<dim3(B * bpb), dim3(256), 0, stream>>>(pred, clean, inst, partials, bpb, npix);
    fl_stage2<<<dim3(B * 8), dim3(128), 0, stream>>>(partials, bres, bpb);
    fl_stage3<<<dim3(1), dim3(128), 0, stream>>>(bres, out);
}

// Round 13
// 234.790 us; speedup vs baseline: 1.0426x; 1.0048x over previous
//
#include <hip/hip_runtime.h>
#include <math.h>

#define NSEG 1024
#define MINPIX 8.0f
#define EPSF 1e-6f

#define QSCALE 8192.0f
#define FMASK ((1ull << 26) - 1)
#define CSHIFT 26
#define NSHIFT 52

typedef unsigned long long u64;
typedef unsigned int u32;

// ---------- PROBE R: deep-MLP 3-stream read of batches 0..7 (100.7 MB).
// 6 independent 16B loads in flight per thread per iteration (no VGPR cap, no
// launch_bounds), 2 accumulator chains. Launched TWICE back-to-back: if #1 is
// much slower than #2, a head-of-sequence interferer (harness restore traffic)
// is stealing bandwidth; #2's rate is the true 3-stream read ceiling.
__global__ void fl_probeR(
    const float* __restrict__ pred, const float* __restrict__ clean,
    const int* __restrict__ inst, u64* __restrict__ sink)
{
    const long long N = 8LL * 1048576;          // 8 batches' pixels
    const int nthr = gridDim.x * 256;
    const long long tid = (long long)blockIdx.x * 256 + threadIdx.x;
    const long long stride = (long long)nthr * 8;

    float s0 = 0.f, s1 = 0.f, s2 = 0.f, s3 = 0.f;
    u32 m0 = 0, m1 = 0;
    for (long long i = tid * 8; i < N; i += stride) {
        const float4 pa = *reinterpret_cast<const float4*>(pred  + i);
        const float4 pb = *reinterpret_cast<const float4*>(pred  + i + 4);
        const float4 ca = *reinterpret_cast<const float4*>(clean + i);
        const float4 cb = *reinterpret_cast<const float4*>(clean + i + 4);
        const int4   ma = *reinterpret_cast<const int4*>(inst   + i);
        const int4   mb = *reinterpret_cast<const int4*>(inst   + i + 4);
        s0 += pa.x + pa.y + pa.z + pa.w;
        s1 += pb.x + pb.y + pb.z + pb.w;
        s2 += ca.x + ca.y + ca.z + ca.w;
        s3 += cb.x + cb.y + cb.z + cb.w;
        m0 ^= (u32)(ma.x + ma.y + ma.z + ma.w);
        m1 ^= (u32)(mb.x + mb.y + mb.z + mb.w);
    }
    sink[tid] = ((u64)__float_as_uint(s0 + s2) << 32)
              ^ (u64)__float_as_uint(s1 + s3) ^ (u64)(m0 ^ m1);
}

// ---------- Stage 1: unchanged R11 (grid-stride-within-batch, 1 u64 atomic/px).
__global__ __launch_bounds__(256) void fl_stage1(
    const float* __restrict__ pred, const float* __restrict__ clean,
    const int* __restrict__ inst, u64* __restrict__ partials,
    int bpb, int npix)
{
    __shared__ u64 s_h[NSEG];
    const int b  = blockIdx.x / bpb;
    const int kb = blockIdx.x - b * bpb;
    for (int i = threadIdx.x; i < NSEG; i += 256) s_h[i] = 0ull;
    __syncthreads();

    const size_t base = (size_t)b * (size_t)npix;
    const int stride = bpb * 256 * 4;

    for (int i = (kb * 256 + (int)threadIdx.x) * 4; i < npix; i += stride) {
        const float4 p4 = *reinterpret_cast<const float4*>(pred  + base + i);
        const float4 c4 = *reinterpret_cast<const float4*>(clean + base + i);
        const int4   m4 = *reinterpret_cast<const int4*>(inst   + base + i);
        {
            const u32 pf = (u32)(p4.x * QSCALE + 0.5f);
            const u32 cf = (u32)(c4.x * QSCALE + 0.5f);
            atomicAdd(&s_h[m4.x], (u64)pf | ((u64)cf << CSHIFT) | (1ull << NSHIFT));
        }
        {
            const u32 pf = (u32)(p4.y * QSCALE + 0.5f);
            const u32 cf = (u32)(c4.y * QSCALE + 0.5f);
            atomicAdd(&s_h[m4.y], (u64)pf | ((u64)cf << CSHIFT) | (1ull << NSHIFT));
        }
        {
            const u32 pf = (u32)(p4.z * QSCALE + 0.5f);
            const u32 cf = (u32)(c4.z * QSCALE + 0.5f);
            atomicAdd(&s_h[m4.z], (u64)pf | ((u64)cf << CSHIFT) | (1ull << NSHIFT));
        }
        {
            const u32 pf = (u32)(p4.w * QSCALE + 0.5f);
            const u32 cf = (u32)(c4.w * QSCALE + 0.5f);
            atomicAdd(&s_h[m4.w], (u64)pf | ((u64)cf << CSHIFT) | (1ull << NSHIFT));
        }
    }
    __syncthreads();

    u64* out = partials + (size_t)blockIdx.x * NSEG;
    for (int i = threadIdx.x; i < NSEG; i += 256) out[i] = s_h[i];
}

// Stage 2: unchanged.
__global__ __launch_bounds__(128) void fl_stage2(
    const u64* __restrict__ partials, float* __restrict__ bres, int bpb)
{
    const int b = blockIdx.x >> 3;
    const int q = blockIdx.x & 7;
    const int s = q * 128 + threadIdx.x;
    const u64* base = partials + (size_t)b * bpb * NSEG + s;

    u32 sp = 0, sc = 0, sn = 0;
    #pragma unroll 8
    for (int k = 0; k < bpb; ++k) {
        const u64 v = base[(size_t)k * NSEG];
        sp += (u32)(v & FMASK);
        sc += (u32)((v >> CSHIFT) & FMASK);
        sn += (u32)(v >> NSHIFT);
    }
    const float cn  = (float)sn;
    const float den = fmaxf(cn, 1.0f);
    const float pm  = ((float)sp * (1.0f / QSCALE)) / den;
    const float tm  = ((float)sc * (1.0f / QSCALE)) / den;
    const bool  valid = (cn >= MINPIX) && (s > 0);
    const float v  = valid ? 1.0f : 0.0f;
    const float pc = fminf(fmaxf(pm, EPSF), 1.0f - EPSF);
    const float bce = -(tm * logf(pc) + (1.0f - tm) * log1pf(-pc));
    const float tmask = (valid && tm > 0.5f) ? 1.0f : 0.0f;
    const float nmask = (valid && tm <= 0.5f) ? 1.0f : 0.0f;

    float vals[6];
    vals[0] = bce * v;
    vals[1] = v;
    vals[2] = pm * tmask;
    vals[3] = tmask;
    vals[4] = pm * nmask;
    vals[5] = nmask;

    #pragma unroll
    for (int off = 32; off > 0; off >>= 1)
        #pragma unroll
        for (int j = 0; j < 6; ++j) vals[j] += __shfl_down(vals[j], off);

    __shared__ float red[2][6];
    const int wid  = threadIdx.x >> 6;
    const int lane = threadIdx.x & 63;
    if (lane == 0)
        for (int j = 0; j < 6; ++j) red[wid][j] = vals[j];
    __syncthreads();
    if (threadIdx.x == 0)
        for (int j = 0; j < 6; ++j) bres[blockIdx.x * 6 + j] = red[0][j] + red[1][j];
}

// Stage 3: unchanged.
__global__ __launch_bounds__(128) void fl_stage3(
    const float* __restrict__ bres, float* __restrict__ out)
{
    const int i = threadIdx.x;
    float v[6];
    #pragma unroll
    for (int j = 0; j < 6; ++j) v[j] = bres[i * 6 + j];

    #pragma unroll
    for (int off = 4; off > 0; off >>= 1)
        #pragma unroll
        for (int j = 0; j < 6; ++j) v[j] += __shfl_down(v[j], off, 8);

    float acc[6] = {0.f, 0.f, 0.f, 0.f, 0.f, 0.f};
    if ((i & 7) == 0) {
        const float loss_b = v[0] / fmaxf(v[1], 1.0f);
        const float bv = (v[1] > 0.f) ? 1.f : 0.f;
        const float ct = v[2] / fmaxf(v[3], 1.0f);
        const float ht = (v[3] > 0.f) ? 1.f : 0.f;
        const float cm = v[4] / fmaxf(v[5], 1.0f);
        const float hn = (v[5] > 0.f) ? 1.f : 0.f;
        acc[0] = loss_b * bv; acc[1] = bv;
        acc[2] = ct * ht;     acc[3] = ht;
        acc[4] = cm * hn;     acc[5] = hn;
    }

    #pragma unroll
    for (int off = 32; off > 0; off >>= 1)
        #pragma unroll
        for (int j = 0; j < 6; ++j) acc[j] += __shfl_down(acc[j], off);

    __shared__ float red[2][6];
    const int wid  = threadIdx.x >> 6;
    const int lane = threadIdx.x & 63;
    if (lane == 0)
        for (int j = 0; j < 6; ++j) red[wid][j] = acc[j];
    __syncthreads();
    if (threadIdx.x == 0) {
        float r[6];
        for (int j = 0; j < 6; ++j) r[j] = red[0][j] + red[1][j];
        const float vc = r[1];
        out[0] = (vc > 0.f) ? r[0] / fmaxf(vc, 1.f) : 0.0f;
        out[1] = 0.0f;
        out[2] = (vc > 0.f && r[3] > 0.f) ? r[2] / fmaxf(r[3], 1.f) : -1.0f;
        out[3] = (vc > 0.f && r[5] > 0.f) ? r[4] / fmaxf(r[5], 1.f) : -1.0f;
    }
}

extern "C" void kernel_launch(void* const* d_in, const int* in_sizes, int n_in,
                              void* d_out, int out_size, void* d_ws, size_t ws_size,
                              hipStream_t stream)
{
    const float* pred  = (const float*)d_in[0];
    const float* clean = (const float*)d_in[1];
    const int*   inst  = (const int*)d_in[2];
    float* out = (float*)d_out;

    const int B = 16;
    const int total = in_sizes[0];          // 16777216
    const int npix  = total / B;

    const size_t per_blk_bytes = (size_t)NSEG * sizeof(u64);        // 8 KB
    int bpb = 128;                                                   // 2048 blocks
    const int PROBE_BLOCKS = 1024;
    for (;;) {
        const size_t partials_b = (size_t)B * bpb * per_blk_bytes;   // 16 MB
        const size_t sinks_b    = 2 * (size_t)PROBE_BLOCKS * 256 * sizeof(u64); // 4 MB
        const size_t bres_b     = (size_t)B * 8 * 6 * sizeof(float);
        if (partials_b + sinks_b + bres_b <= ws_size || bpb == 1) break;
        bpb >>= 1;
    }

    u64*   partials = (u64*)d_ws;
    u64*   sink1    = (u64*)((char*)d_ws + (size_t)B * bpb * per_blk_bytes);
    u64*   sink2    = sink1 + (size_t)PROBE_BLOCKS * 256;
    float* bres     = (float*)(sink2 + (size_t)PROBE_BLOCKS * 256);

    // Twin probes: identical kernels back-to-back. #1 vs #2 duration delta
    // isolates head-of-sequence interference from genuine BW ceiling.
    fl_probeR<<<dim3(PROBE_BLOCKS), dim3(256), 0, stream>>>(pred, clean, inst, sink1);
    fl_probeR<<<dim3(PROBE_BLOCKS), dim3(256), 0, stream>>>(pred, clean, inst, sink2);

    // Real pipeline (R11 form, unchanged).
    fl_stage1<<<dim3(B * bpb), dim3(256), 0, stream>>>(pred, clean, inst, partials, bpb, npix);
    fl_stage2<<<dim3(B * 8), dim3(128), 0, stream>>>(partials, bres, bpb);
    fl_stage3<<<dim3(1), dim3(128), 0, stream>>>(bres, out);
}

// Round 15
// 213.348 us; speedup vs baseline: 1.1474x; 1.1005x over previous
//
#include <hip/hip_runtime.h>
#include <math.h>

#define NSEG 1024
#define MINPIX 8.0f
#define EPSF 1e-6f

#define QSCALE 8192.0f
#define FMASK ((1ull << 26) - 1)
#define CSHIFT 26
#define NSHIFT 52

typedef unsigned long long u64;
typedef unsigned int u32;

// Stage 1: grid-stride-within-batch, 1 packed u64 LDS atomic per pixel.
// R13 measured this body at 50.5us @ 4.0 TB/s delivered when running clean
// (third in sequence); the ~25us penalty when first is harness restore
// traffic sharing bandwidth, not a kernel property.
__global__ __launch_bounds__(256) void fl_stage1(
    const float* __restrict__ pred, const float* __restrict__ clean,
    const int* __restrict__ inst, u64* __restrict__ partials,
    int bpb, int npix)
{
    __shared__ u64 s_h[NSEG];
    const int b  = blockIdx.x / bpb;
    const int kb = blockIdx.x - b * bpb;
    for (int i = threadIdx.x; i < NSEG; i += 256) s_h[i] = 0ull;
    __syncthreads();

    const size_t base = (size_t)b * (size_t)npix;
    const int stride = bpb * 256 * 4;

    for (int i = (kb * 256 + (int)threadIdx.x) * 4; i < npix; i += stride) {
        const float4 p4 = *reinterpret_cast<const float4*>(pred  + base + i);
        const float4 c4 = *reinterpret_cast<const float4*>(clean + base + i);
        const int4   m4 = *reinterpret_cast<const int4*>(inst   + base + i);
        {
            const u32 pf = (u32)(p4.x * QSCALE + 0.5f);
            const u32 cf = (u32)(c4.x * QSCALE + 0.5f);
            atomicAdd(&s_h[m4.x], (u64)pf | ((u64)cf << CSHIFT) | (1ull << NSHIFT));
        }
        {
            const u32 pf = (u32)(p4.y * QSCALE + 0.5f);
            const u32 cf = (u32)(c4.y * QSCALE + 0.5f);
            atomicAdd(&s_h[m4.y], (u64)pf | ((u64)cf << CSHIFT) | (1ull << NSHIFT));
        }
        {
            const u32 pf = (u32)(p4.z * QSCALE + 0.5f);
            const u32 cf = (u32)(c4.z * QSCALE + 0.5f);
            atomicAdd(&s_h[m4.z], (u64)pf | ((u64)cf << CSHIFT) | (1ull << NSHIFT));
        }
        {
            const u32 pf = (u32)(p4.w * QSCALE + 0.5f);
            const u32 cf = (u32)(c4.w * QSCALE + 0.5f);
            atomicAdd(&s_h[m4.w], (u64)pf | ((u64)cf << CSHIFT) | (1ull << NSHIFT));
        }
    }
    __syncthreads();

    u64* out = partials + (size_t)blockIdx.x * NSEG;
    for (int i = threadIdx.x; i < NSEG; i += 256) out[i] = s_h[i];
}

// Stage 2: B*8 blocks x 128 thr; thread owns one segment, sums bpb partials
// (fields unpacked), computes per-cell epilogue, block-reduces 6 quantities.
__global__ __launch_bounds__(128) void fl_stage2(
    const u64* __restrict__ partials, float* __restrict__ bres, int bpb)
{
    const int b = blockIdx.x >> 3;
    const int q = blockIdx.x & 7;
    const int s = q * 128 + threadIdx.x;
    const u64* base = partials + (size_t)b * bpb * NSEG + s;

    u32 sp = 0, sc = 0, sn = 0;
    #pragma unroll 8
    for (int k = 0; k < bpb; ++k) {
        const u64 v = base[(size_t)k * NSEG];
        sp += (u32)(v & FMASK);
        sc += (u32)((v >> CSHIFT) & FMASK);
        sn += (u32)(v >> NSHIFT);
    }
    const float cn  = (float)sn;
    const float den = fmaxf(cn, 1.0f);
    const float pm  = ((float)sp * (1.0f / QSCALE)) / den;
    const float tm  = ((float)sc * (1.0f / QSCALE)) / den;
    const bool  valid = (cn >= MINPIX) && (s > 0);
    const float v  = valid ? 1.0f : 0.0f;
    const float pc = fminf(fmaxf(pm, EPSF), 1.0f - EPSF);
    const float bce = -(tm * logf(pc) + (1.0f - tm) * log1pf(-pc));
    const float tmask = (valid && tm > 0.5f) ? 1.0f : 0.0f;
    const float nmask = (valid && tm <= 0.5f) ? 1.0f : 0.0f;

    float vals[6];
    vals[0] = bce * v;
    vals[1] = v;
    vals[2] = pm * tmask;
    vals[3] = tmask;
    vals[4] = pm * nmask;
    vals[5] = nmask;

    #pragma unroll
    for (int off = 32; off > 0; off >>= 1)
        #pragma unroll
        for (int j = 0; j < 6; ++j) vals[j] += __shfl_down(vals[j], off);

    __shared__ float red[2][6];
    const int wid  = threadIdx.x >> 6;
    const int lane = threadIdx.x & 63;
    if (lane == 0)
        for (int j = 0; j < 6; ++j) red[wid][j] = vals[j];
    __syncthreads();
    if (threadIdx.x == 0)
        for (int j = 0; j < 6; ++j) bres[blockIdx.x * 6 + j] = red[0][j] + red[1][j];
}

// Stage 3: one block, 128 threads (16 batches x 8 q-parts).
__global__ __launch_bounds__(128) void fl_stage3(
    const float* __restrict__ bres, float* __restrict__ out)
{
    const int i = threadIdx.x;
    float v[6];
    #pragma unroll
    for (int j = 0; j < 6; ++j) v[j] = bres[i * 6 + j];

    #pragma unroll
    for (int off = 4; off > 0; off >>= 1)
        #pragma unroll
        for (int j = 0; j < 6; ++j) v[j] += __shfl_down(v[j], off, 8);

    float acc[6] = {0.f, 0.f, 0.f, 0.f, 0.f, 0.f};
    if ((i & 7) == 0) {
        const float loss_b = v[0] / fmaxf(v[1], 1.0f);
        const float bv = (v[1] > 0.f) ? 1.f : 0.f;
        const float ct = v[2] / fmaxf(v[3], 1.0f);
        const float ht = (v[3] > 0.f) ? 1.f : 0.f;
        const float cm = v[4] / fmaxf(v[5], 1.0f);
        const float hn = (v[5] > 0.f) ? 1.f : 0.f;
        acc[0] = loss_b * bv; acc[1] = bv;
        acc[2] = ct * ht;     acc[3] = ht;
        acc[4] = cm * hn;     acc[5] = hn;
    }

    #pragma unroll
    for (int off = 32; off > 0; off >>= 1)
        #pragma unroll
        for (int j = 0; j < 6; ++j) acc[j] += __shfl_down(acc[j], off);

    __shared__ float red[2][6];
    const int wid  = threadIdx.x >> 6;
    const int lane = threadIdx.x & 63;
    if (lane == 0)
        for (int j = 0; j < 6; ++j) red[wid][j] = acc[j];
    __syncthreads();
    if (threadIdx.x == 0) {
        float r[6];
        for (int j = 0; j < 6; ++j) r[j] = red[0][j] + red[1][j];
        const float vc = r[1];
        out[0] = (vc > 0.f) ? r[0] / fmaxf(vc, 1.f) : 0.0f;
        out[1] = 0.0f;
        out[2] = (vc > 0.f && r[3] > 0.f) ? r[2] / fmaxf(r[3], 1.f) : -1.0f;
        out[3] = (vc > 0.f && r[5] > 0.f) ? r[4] / fmaxf(r[5], 1.f) : -1.0f;
    }
}

extern "C" void kernel_launch(void* const* d_in, const int* in_sizes, int n_in,
                              void* d_out, int out_size, void* d_ws, size_t ws_size,
                              hipStream_t stream)
{
    const float* pred  = (const float*)d_in[0];
    const float* clean = (const float*)d_in[1];
    const int*   inst  = (const int*)d_in[2];
    float* out = (float*)d_out;

    const int B = 16;
    const int total = in_sizes[0];          // 16777216
    const int npix  = total / B;

    const size_t per_blk_bytes = (size_t)NSEG * sizeof(u64);        // 8 KB
    int bpb = 64;                           // 1024 blocks; halves partials traffic vs 128
    for (;;) {
        const size_t partials_b = (size_t)B * bpb * per_blk_bytes;   // 8 MB @ bpb=64
        const size_t bres_b     = (size_t)B * 8 * 6 * sizeof(float);
        if (partials_b + bres_b <= ws_size || bpb == 1) break;
        bpb >>= 1;
    }

    u64*   partials = (u64*)d_ws;
    float* bres     = (float*)((char*)d_ws + (size_t)B * bpb * per_blk_bytes);

    fl_stage1<<<dim3(B * bpb), dim3(256), 0, stream>>>(pred, clean, inst, partials, bpb, npix);
    fl_stage2<<<dim3(B * 8), dim3(128), 0, stream>>>(partials, bres, bpb);
    fl_stage3<<<dim3(1), dim3(128), 0, stream>>>(bres, out);
}